// Round 8
// baseline (348.610 us; speedup 1.0000x reference)
//
#include <hip/hip_runtime.h>
#include <math.h>

#define B_TOK 2048
#define DMODEL 1024
#define HDIM 4096
#define NEXP 8
#define TOPK 2

#define BM 128
#define BK 64
#define MAX_TILES 40

typedef __attribute__((ext_vector_type(8))) short bf16x8;
typedef __attribute__((ext_vector_type(4))) float f32x4;

__device__ __forceinline__ unsigned short f2b(float f) {
  unsigned u = __builtin_bit_cast(unsigned, f);
  unsigned r = (u + 0x7FFFu + ((u >> 16) & 1u)) >> 16;
  return (unsigned short)r;
}

__device__ __forceinline__ void load_lds16(const void* g, void* l) {
  __builtin_amdgcn_global_load_lds(
      (const __attribute__((address_space(1))) unsigned int*)g,
      (__attribute__((address_space(3))) unsigned int*)l, 16, 0, 0);
}

// ---------------- gate: logits (f64 accum) -> top2 -> softmax ----------------
__global__ __launch_bounds__(256) void gate_kernel(
    const float* __restrict__ x, const float* __restrict__ gw,
    const float* __restrict__ gb, int* __restrict__ idx2,
    float* __restrict__ sc2, int* __restrict__ counts) {
  int lane = threadIdx.x & 63;
  int w = threadIdx.x >> 6;
  int b = blockIdx.x * 4 + w;
  double acc[NEXP];
#pragma unroll
  for (int e = 0; e < NEXP; ++e) acc[e] = 0.0;
  const float* xr = x + (size_t)b * DMODEL;
#pragma unroll
  for (int i = 0; i < 4; ++i) {
    float4 xv = *(const float4*)(xr + i * 256 + lane * 4);
#pragma unroll
    for (int e = 0; e < NEXP; ++e) {
      float4 wv = *(const float4*)(gw + e * DMODEL + i * 256 + lane * 4);
      acc[e] += (double)xv.x * wv.x + (double)xv.y * wv.y +
                (double)xv.z * wv.z + (double)xv.w * wv.w;
    }
  }
#pragma unroll
  for (int e = 0; e < NEXP; ++e) {
    double v = acc[e];
    for (int o = 1; o < 64; o <<= 1) v += __shfl_xor(v, o, 64);
    acc[e] = v + (double)gb[e];
  }
  if (lane == 0) {
    int i0 = 0;
    double v0 = acc[0];
#pragma unroll
    for (int e = 1; e < NEXP; ++e)
      if (acc[e] > v0) { v0 = acc[e]; i0 = e; }
    int i1 = -1;
    double v1 = -1e300;
#pragma unroll
    for (int e = 0; e < NEXP; ++e)
      if (e != i0 && acc[e] > v1) { v1 = acc[e]; i1 = e; }
    double t = exp(v1 - v0);
    float s0 = (float)(1.0 / (1.0 + t));
    float s1 = (float)(t / (1.0 + t));
    idx2[b * 2] = i0;
    idx2[b * 2 + 1] = i1;
    sc2[b * 2] = s0;
    sc2[b * 2 + 1] = s1;
    atomicAdd(&counts[i0], 1);
    atomicAdd(&counts[i1], 1);
  }
}

// ---------------- plan: prefix offsets + tile map (1 thread) ----------------
__global__ void plan_kernel(const int* __restrict__ counts, int* __restrict__ offsets,
                            int* __restrict__ tile_map, int* __restrict__ ntiles,
                            int* __restrict__ cursors) {
  int off = 0;
  offsets[0] = 0;
  for (int e = 0; e < NEXP; ++e) {
    off += counts[e];
    offsets[e + 1] = off;
    cursors[e] = 0;
  }
  int tt = 0;
  for (int e = 0; e < NEXP; ++e) {
    int cnt = counts[e];
    int base = offsets[e];
    for (int t = 0; t * BM < cnt; ++t) {
      tile_map[tt * 4 + 0] = e;
      tile_map[tt * 4 + 1] = base + t * BM;
      tile_map[tt * 4 + 2] = (cnt - t * BM) < BM ? (cnt - t * BM) : BM;
      tile_map[tt * 4 + 3] = 0;
      ++tt;
    }
  }
  *ntiles = tt;
}

// ---------------- scatter: (b,k) -> pos; also pos->token/score ----------------
__global__ __launch_bounds__(256) void scatter_kernel(
    const int* __restrict__ idx2, const float* __restrict__ sc2,
    const int* __restrict__ offsets, int* __restrict__ cursors,
    int* __restrict__ pos_of, int* __restrict__ row_of, float* __restrict__ s_of) {
  int t = blockIdx.x * 256 + threadIdx.x;
  if (t < B_TOK * TOPK) {
    int e = idx2[t];
    int p = offsets[e] + atomicAdd(&cursors[e], 1);
    pos_of[t] = p;
    row_of[p] = t >> 1;
    s_of[p] = sc2[t];
  }
}

// ---------------- gather: permuted bf16 activations ----------------
__global__ __launch_bounds__(256) void gather_kernel(
    const float* __restrict__ x, const int* __restrict__ row_of,
    unsigned short* __restrict__ Xp) {
  int r = blockIdx.x;
  int tok = row_of[r];
  int c = threadIdx.x * 4;
  float4 v = *(const float4*)(x + (size_t)tok * DMODEL + c);
  ushort4 o = make_ushort4(f2b(v.x), f2b(v.y), f2b(v.z), f2b(v.w));
  *(ushort4*)(Xp + (size_t)r * DMODEL + c) = o;
}

// ---- transpose+convert: W[e][k][n] f32 -> Wt[e][n][k] bf16 (u32 k-pair pack) ----
// 64x64 tile. Write/read LDS banks both exactly 2-way (stride 33 words).
// XCD-swizzled block remap: blocks sharing source rows cluster on one XCD's L2.
__global__ __launch_bounds__(256) void convT_kernel(
    const float* __restrict__ W, unsigned short* __restrict__ Wt, int Kd, int Nd,
    int tilesN, int cpx) {
  __shared__ unsigned L[64 * 33];
  int bidx = (blockIdx.x & 7) * cpx + (blockIdx.x >> 3);  // bijective: grid%8==0
  int nt = bidx % tilesN;
  int r2 = bidx / tilesN;
  int tilesK = Kd >> 6;
  int kt = r2 % tilesK;
  int e = r2 / tilesK;
  int tid = threadIdx.x;

  const float* src = W + (long)e * Kd * Nd + (long)(kt * 64) * Nd + nt * 64;
  int kp = tid >> 3;
  int nb = tid & 7;
  const float* r0 = src + (long)(2 * kp) * Nd + nb * 8;
  const float* r1 = r0 + Nd;
  float4 va0 = *(const float4*)r0;
  float4 va1 = *(const float4*)(r0 + 4);
  float4 vb0 = *(const float4*)r1;
  float4 vb1 = *(const float4*)(r1 + 4);
  const float* a = (const float*)&va0;
  const float* bq = (const float*)&vb0;
#pragma unroll
  for (int j = 0; j < 4; ++j) {
    unsigned p = (unsigned)f2b(a[j]) | ((unsigned)f2b(bq[j]) << 16);
    L[(nb * 8 + j) * 33 + kp] = p;
  }
  const float* a2 = (const float*)&va1;
  const float* b2 = (const float*)&vb1;
#pragma unroll
  for (int j = 0; j < 4; ++j) {
    unsigned p = (unsigned)f2b(a2[j]) | ((unsigned)f2b(b2[j]) << 16);
    L[(nb * 8 + 4 + j) * 33 + kp] = p;
  }
  __syncthreads();
  int n = tid >> 2;
  int part = tid & 3;
  unsigned q[8];
#pragma unroll
  for (int j = 0; j < 8; ++j) q[j] = L[n * 33 + part * 8 + j];
  unsigned* dst = (unsigned*)(Wt + (long)e * Nd * Kd + (long)(nt * 64 + n) * Kd +
                              kt * 64) +
                  part * 8;
  *(uint4*)dst = make_uint4(q[0], q[1], q[2], q[3]);
  *(uint4*)(dst + 4) = make_uint4(q[4], q[5], q[6], q[7]);
}

// ---------------- grouped GEMM (m97 structure, PROVEN body — round-5 text) ----------------
// OMODE 0: f32 store; 1: bf16 store; 2: f32 atomicAdd of s*(acc+bias) into out[token]
template <int BN_, int WM, int WN, bool GELU, int OMODE>
__global__ __launch_bounds__(256) void gemm_bt(
    const unsigned short* __restrict__ A, int lda,
    const unsigned short* __restrict__ Bt, long strideB,
    const float* __restrict__ bias, int strideBias, void* __restrict__ Cout,
    int ldc, const int* __restrict__ row_of, const float* __restrict__ s_of,
    const int* __restrict__ tile_map, const int* __restrict__ ntiles, int N,
    int K) {
  const int nb = N / BN_;
  const int tile = blockIdx.x / nb;
  if (tile >= *ntiles) return;
  const int ct = blockIdx.x % nb;
  const int e = tile_map[tile * 4 + 0];
  const int row0 = tile_map[tile * 4 + 1];
  const int rows = tile_map[tile * 4 + 2];
  const int n0 = ct * BN_;
  const unsigned short* B_e = Bt + (long)e * strideB + (long)n0 * K;

  __shared__ __align__(16) unsigned short Asm[BM * BK];
  __shared__ __align__(16) unsigned short Bsm[BN_ * BK];

  const int tid = threadIdx.x;
  const int lane = tid & 63;
  const int w = tid >> 6;
  const int WTM = BM / WM, WTN = BN_ / WN;
  const int wr = (w / WN) * WTM;
  const int wc = (w % WN) * WTN;
  const int MR = WTM / 16, NR = WTN / 16;
  const int l15 = lane & 15;
  const int l4 = lane >> 4;

  f32x4 acc[MR][NR] = {};

  for (int k0 = 0; k0 < K; k0 += BK) {
#pragma unroll
    for (int it = 0; it < 4; ++it) {
      int c = it * 256 + tid;
      int r = c >> 3, kc = c & 7;
      int kcs = kc ^ (r & 7);
      load_lds16(A + (size_t)(row0 + r) * lda + k0 + kcs * 8,
                 ((char*)Asm) + (size_t)(it * 256 + w * 64) * 16);
    }
#pragma unroll
    for (int it = 0; it < BN_ / 32; ++it) {
      int c = it * 256 + tid;
      int r = c >> 3, kc = c & 7;
      int kcs = kc ^ (r & 7);
      load_lds16(B_e + (size_t)r * K + k0 + kcs * 8,
                 ((char*)Bsm) + (size_t)(it * 256 + w * 64) * 16);
    }
    __syncthreads();
#pragma unroll
    for (int kk = 0; kk < 2; ++kk) {
      bf16x8 a[MR], b[NR];
#pragma unroll
      for (int m = 0; m < MR; ++m) {
        int row = wr + m * 16 + l15;
        int ch = (kk * 4 + l4) ^ (l15 & 7);
        a[m] = *(const bf16x8*)&Asm[row * BK + ch * 8];
      }
#pragma unroll
      for (int n = 0; n < NR; ++n) {
        int row = wc + n * 16 + l15;
        int ch = (kk * 4 + l4) ^ (l15 & 7);
        b[n] = *(const bf16x8*)&Bsm[row * BK + ch * 8];
      }
#pragma unroll
      for (int m = 0; m < MR; ++m)
#pragma unroll
        for (int n = 0; n < NR; ++n)
          acc[m][n] =
              __builtin_amdgcn_mfma_f32_16x16x32_bf16(a[m], b[n], acc[m][n], 0, 0, 0);
    }
    __syncthreads();
  }

  const float* bias_e = bias + (long)e * strideBias;
#pragma unroll
  for (int m = 0; m < MR; ++m) {
#pragma unroll
    for (int i = 0; i < 4; ++i) {
      int r = wr + m * 16 + l4 * 4 + i;
      if (r < rows) {
        if (OMODE == 2) {
          int tok = row_of[row0 + r];
          float s = s_of[row0 + r];
          float* op = (float*)Cout + (size_t)tok * ldc;
#pragma unroll
          for (int n = 0; n < NR; ++n) {
            int cg = n0 + wc + n * 16 + l15;
            float v = acc[m][n][i] + bias_e[cg];
            atomicAdd(&op[cg], s * v);
          }
        } else {
          size_t grow = (size_t)(row0 + r) * ldc;
#pragma unroll
          for (int n = 0; n < NR; ++n) {
            int cg = n0 + wc + n * 16 + l15;
            float v = acc[m][n][i] + bias_e[cg];
            if (GELU) v = 0.5f * v * (1.0f + erff(v * 0.70710678118654752f));
            if (OMODE == 1)
              ((unsigned short*)Cout)[grow + cg] = f2b(v);
            else
              ((float*)Cout)[grow + cg] = v;
          }
        }
      }
    }
  }
}

// -------- G2-only: split-K copy of the proven body (separate symbol) --------
// grid = ntiles * nb * SPLITK; ks-th block handles K-range [ks*K/SPLITK, ...).
// Atomic combine: out[token] += s*(acc [+bias if ks==0]).
template <int BN_, int WM, int WN, int SPLITK>
__global__ __launch_bounds__(256) void gemm_sk(
    const unsigned short* __restrict__ A, int lda,
    const unsigned short* __restrict__ Bt, long strideB,
    const float* __restrict__ bias, int strideBias, float* __restrict__ Cout,
    int ldc, const int* __restrict__ row_of, const float* __restrict__ s_of,
    const int* __restrict__ tile_map, const int* __restrict__ ntiles, int N,
    int K) {
  const int nb = N / BN_;
  const int ks = blockIdx.x & (SPLITK - 1);
  const int bid = blockIdx.x >> (SPLITK == 2 ? 1 : (SPLITK == 4 ? 2 : 0));
  const int tile = bid / nb;
  if (tile >= *ntiles) return;
  const int ct = bid % nb;
  const int e = tile_map[tile * 4 + 0];
  const int row0 = tile_map[tile * 4 + 1];
  const int rows = tile_map[tile * 4 + 2];
  const int n0 = ct * BN_;
  const unsigned short* B_e = Bt + (long)e * strideB + (long)n0 * K;

  __shared__ __align__(16) unsigned short Asm[BM * BK];
  __shared__ __align__(16) unsigned short Bsm[BN_ * BK];

  const int tid = threadIdx.x;
  const int lane = tid & 63;
  const int w = tid >> 6;
  const int WTM = BM / WM, WTN = BN_ / WN;
  const int wr = (w / WN) * WTM;
  const int wc = (w % WN) * WTN;
  const int MR = WTM / 16, NR = WTN / 16;
  const int l15 = lane & 15;
  const int l4 = lane >> 4;

  f32x4 acc[MR][NR] = {};

  const int kbeg = ks * (K / SPLITK);
  const int kend = kbeg + (K / SPLITK);
  for (int k0 = kbeg; k0 < kend; k0 += BK) {
#pragma unroll
    for (int it = 0; it < 4; ++it) {
      int c = it * 256 + tid;
      int r = c >> 3, kc = c & 7;
      int kcs = kc ^ (r & 7);
      load_lds16(A + (size_t)(row0 + r) * lda + k0 + kcs * 8,
                 ((char*)Asm) + (size_t)(it * 256 + w * 64) * 16);
    }
#pragma unroll
    for (int it = 0; it < BN_ / 32; ++it) {
      int c = it * 256 + tid;
      int r = c >> 3, kc = c & 7;
      int kcs = kc ^ (r & 7);
      load_lds16(B_e + (size_t)r * K + k0 + kcs * 8,
                 ((char*)Bsm) + (size_t)(it * 256 + w * 64) * 16);
    }
    __syncthreads();
#pragma unroll
    for (int kk = 0; kk < 2; ++kk) {
      bf16x8 a[MR], b[NR];
#pragma unroll
      for (int m = 0; m < MR; ++m) {
        int row = wr + m * 16 + l15;
        int ch = (kk * 4 + l4) ^ (l15 & 7);
        a[m] = *(const bf16x8*)&Asm[row * BK + ch * 8];
      }
#pragma unroll
      for (int n = 0; n < NR; ++n) {
        int row = wc + n * 16 + l15;
        int ch = (kk * 4 + l4) ^ (l15 & 7);
        b[n] = *(const bf16x8*)&Bsm[row * BK + ch * 8];
      }
#pragma unroll
      for (int m = 0; m < MR; ++m)
#pragma unroll
        for (int n = 0; n < NR; ++n)
          acc[m][n] =
              __builtin_amdgcn_mfma_f32_16x16x32_bf16(a[m], b[n], acc[m][n], 0, 0, 0);
    }
    __syncthreads();
  }

  const float* bias_e = bias + (long)e * strideBias;
#pragma unroll
  for (int m = 0; m < MR; ++m) {
#pragma unroll
    for (int i = 0; i < 4; ++i) {
      int r = wr + m * 16 + l4 * 4 + i;
      if (r < rows) {
        int tok = row_of[row0 + r];
        float s = s_of[row0 + r];
        float* op = Cout + (size_t)tok * ldc;
#pragma unroll
        for (int n = 0; n < NR; ++n) {
          int cg = n0 + wc + n * 16 + l15;
          float v = acc[m][n][i];
          if (ks == 0) v += bias_e[cg];
          atomicAdd(&op[cg], s * v);
        }
      }
    }
  }
}

extern "C" void kernel_launch(void* const* d_in, const int* in_sizes, int n_in,
                              void* d_out, int out_size, void* d_ws, size_t ws_size,
                              hipStream_t stream) {
  const float* x = (const float*)d_in[0];
  const float* gw = (const float*)d_in[1];
  const float* gb = (const float*)d_in[2];
  const float* w1 = (const float*)d_in[3];
  const float* b1 = (const float*)d_in[4];
  const float* w2 = (const float*)d_in[5];
  const float* b2 = (const float*)d_in[6];
  float* out = (float*)d_out;
  char* ws = (char*)d_ws;

  int* counts = (int*)(ws + 0);
  int* cursors = (int*)(ws + 64);
  int* ntiles = (int*)(ws + 128);
  int* offsets = (int*)(ws + 192);
  int* tile_map = (int*)(ws + 256);
  int* idx2 = (int*)(ws + 4096);
  float* sc2 = (float*)(ws + 20480);
  int* pos_of = (int*)(ws + 36864);
  int* row_of = (int*)(ws + 53248);
  float* s_of = (float*)(ws + 73728);
  unsigned short* Xp = (unsigned short*)(ws + 131072);    // 4224x1024 bf16
  unsigned short* H1 = (unsigned short*)(ws + 8781824);   // 4224x4096 bf16
  unsigned short* Wt = (unsigned short*)(ws + 43384832);  // 8x4096x1024 bf16
  if (ws_size < 110493696ULL) return;

  // keep round-5 instantiation set alive for codegen stability (rule #19)
  (void)&gemm_bt<64, 4, 1, false, 2>;

  hipMemsetAsync(counts, 0, 64, stream);
  hipMemsetAsync(out, 0, (size_t)B_TOK * DMODEL * 4, stream);
  gate_kernel<<<B_TOK / 4, 256, 0, stream>>>(x, gw, gb, idx2, sc2, counts);
  plan_kernel<<<1, 1, 0, stream>>>(counts, offsets, tile_map, ntiles, cursors);
  scatter_kernel<<<(B_TOK * TOPK) / 256, 256, 0, stream>>>(idx2, sc2, offsets,
                                                           cursors, pos_of, row_of,
                                                           s_of);
  gather_kernel<<<B_TOK * TOPK, 256, 0, stream>>>(x, row_of, Xp);

  // w1 [E][D][H] f32 -> Wt [E][H][D] bf16  (grid 8192, cpx=1024)
  convT_kernel<<<NEXP * (DMODEL / 64) * (HDIM / 64), 256, 0, stream>>>(
      w1, Wt, DMODEL, HDIM, HDIM / 64, NEXP * (DMODEL / 64) * (HDIM / 64) / 8);
  gemm_bt<128, 2, 2, true, 1><<<MAX_TILES * (HDIM / 128), 256, 0, stream>>>(
      Xp, DMODEL, Wt, (long)HDIM * DMODEL, b1, HDIM, H1, HDIM, nullptr, nullptr,
      tile_map, ntiles, HDIM, DMODEL);
  // w2 [E][H][D] f32 -> Wt [E][D][H] bf16 (reuse buffer; grid 8192, cpx=1024)
  convT_kernel<<<NEXP * (HDIM / 64) * (DMODEL / 64), 256, 0, stream>>>(
      w2, Wt, HDIM, DMODEL, DMODEL / 64, NEXP * (HDIM / 64) * (DMODEL / 64) / 8);
  // GEMM2: proven BN=64 shape + split-K=2 (1280 blocks = 5/CU exact)
  gemm_sk<64, 4, 1, 2><<<MAX_TILES * (DMODEL / 64) * 2, 256, 0, stream>>>(
      H1, HDIM, Wt, (long)DMODEL * HDIM, b2, DMODEL, out, DMODEL, row_of, s_of,
      tile_map, ntiles, DMODEL, HDIM);
}

// Round 9
// 338.186 us; speedup vs baseline: 1.0308x; 1.0308x over previous
//
#include <hip/hip_runtime.h>
#include <math.h>

#define B_TOK 2048
#define DMODEL 1024
#define HDIM 4096
#define NEXP 8
#define TOPK 2

#define BM 128
#define BK 64
#define MAX_TILES 40

typedef __attribute__((ext_vector_type(8))) short bf16x8;
typedef __attribute__((ext_vector_type(4))) float f32x4;

__device__ __forceinline__ unsigned short f2b(float f) {
  unsigned u = __builtin_bit_cast(unsigned, f);
  unsigned r = (u + 0x7FFFu + ((u >> 16) & 1u)) >> 16;
  return (unsigned short)r;
}

__device__ __forceinline__ void load_lds16(const void* g, void* l) {
  __builtin_amdgcn_global_load_lds(
      (const __attribute__((address_space(1))) unsigned int*)g,
      (__attribute__((address_space(3))) unsigned int*)l, 16, 0, 0);
}

// exact-gelu via branchless A&S 7.1.26 erf (|err| <= 1.5e-7, << bf16 ulp)
__device__ __forceinline__ float gelu_fast(float v) {
  float x = v * 0.70710678118654752f;
  float ax = fabsf(x);
  float t = 1.0f / (1.0f + 0.3275911f * ax);
  float e = exp2f(-ax * ax * 1.4426950408889634f);
  float p = t * (0.254829592f +
                 t * (-0.284496736f +
                      t * (1.421413741f +
                           t * (-1.453152027f + t * 1.061405429f))));
  float er = 1.0f - p * e;
  er = copysignf(er, x);
  return 0.5f * v * (1.0f + er);
}

// ---------------- gate: logits (f64 accum) -> top2 -> softmax ----------------
__global__ __launch_bounds__(256) void gate_kernel(
    const float* __restrict__ x, const float* __restrict__ gw,
    const float* __restrict__ gb, int* __restrict__ idx2,
    float* __restrict__ sc2, int* __restrict__ counts) {
  int lane = threadIdx.x & 63;
  int w = threadIdx.x >> 6;
  int b = blockIdx.x * 4 + w;
  double acc[NEXP];
#pragma unroll
  for (int e = 0; e < NEXP; ++e) acc[e] = 0.0;
  const float* xr = x + (size_t)b * DMODEL;
#pragma unroll
  for (int i = 0; i < 4; ++i) {
    float4 xv = *(const float4*)(xr + i * 256 + lane * 4);
#pragma unroll
    for (int e = 0; e < NEXP; ++e) {
      float4 wv = *(const float4*)(gw + e * DMODEL + i * 256 + lane * 4);
      acc[e] += (double)xv.x * wv.x + (double)xv.y * wv.y +
                (double)xv.z * wv.z + (double)xv.w * wv.w;
    }
  }
#pragma unroll
  for (int e = 0; e < NEXP; ++e) {
    double v = acc[e];
    for (int o = 1; o < 64; o <<= 1) v += __shfl_xor(v, o, 64);
    acc[e] = v + (double)gb[e];
  }
  if (lane == 0) {
    int i0 = 0;
    double v0 = acc[0];
#pragma unroll
    for (int e = 1; e < NEXP; ++e)
      if (acc[e] > v0) { v0 = acc[e]; i0 = e; }
    int i1 = -1;
    double v1 = -1e300;
#pragma unroll
    for (int e = 0; e < NEXP; ++e)
      if (e != i0 && acc[e] > v1) { v1 = acc[e]; i1 = e; }
    double t = exp(v1 - v0);
    float s0 = (float)(1.0 / (1.0 + t));
    float s1 = (float)(t / (1.0 + t));
    idx2[b * 2] = i0;
    idx2[b * 2 + 1] = i1;
    sc2[b * 2] = s0;
    sc2[b * 2 + 1] = s1;
    atomicAdd(&counts[i0], 1);
    atomicAdd(&counts[i1], 1);
  }
}

// ---------------- plan: prefix offsets + tile map (1 thread) ----------------
__global__ void plan_kernel(const int* __restrict__ counts, int* __restrict__ offsets,
                            int* __restrict__ tile_map, int* __restrict__ ntiles,
                            int* __restrict__ cursors) {
  int off = 0;
  offsets[0] = 0;
  for (int e = 0; e < NEXP; ++e) {
    off += counts[e];
    offsets[e + 1] = off;
    cursors[e] = 0;
  }
  int tt = 0;
  for (int e = 0; e < NEXP; ++e) {
    int cnt = counts[e];
    int base = offsets[e];
    for (int t = 0; t * BM < cnt; ++t) {
      tile_map[tt * 4 + 0] = e;
      tile_map[tt * 4 + 1] = base + t * BM;
      tile_map[tt * 4 + 2] = (cnt - t * BM) < BM ? (cnt - t * BM) : BM;
      tile_map[tt * 4 + 3] = 0;
      ++tt;
    }
  }
  *ntiles = tt;
}

// ---------------- scatter: (b,k) -> pos; also pos->token/score ----------------
__global__ __launch_bounds__(256) void scatter_kernel(
    const int* __restrict__ idx2, const float* __restrict__ sc2,
    const int* __restrict__ offsets, int* __restrict__ cursors,
    int* __restrict__ pos_of, int* __restrict__ row_of, float* __restrict__ s_of) {
  int t = blockIdx.x * 256 + threadIdx.x;
  if (t < B_TOK * TOPK) {
    int e = idx2[t];
    int p = offsets[e] + atomicAdd(&cursors[e], 1);
    pos_of[t] = p;
    row_of[p] = t >> 1;
    s_of[p] = sc2[t];
  }
}

// ---------------- gather: permuted bf16 activations ----------------
__global__ __launch_bounds__(256) void gather_kernel(
    const float* __restrict__ x, const int* __restrict__ row_of,
    unsigned short* __restrict__ Xp) {
  int r = blockIdx.x;
  int tok = row_of[r];
  int c = threadIdx.x * 4;
  float4 v = *(const float4*)(x + (size_t)tok * DMODEL + c);
  ushort4 o = make_ushort4(f2b(v.x), f2b(v.y), f2b(v.z), f2b(v.w));
  *(ushort4*)(Xp + (size_t)r * DMODEL + c) = o;
}

// ---- transpose+convert: W[e][k][n] f32 -> Wt[e][n][k] bf16 (u32 k-pair pack) ----
// 64x64 tile. Write/read LDS banks both exactly 2-way (stride 33 words).
// XCD-swizzled block remap (bijective, grid%8==0): same-row tiles share an XCD L2.
__global__ __launch_bounds__(256) void convT_kernel(
    const float* __restrict__ W, unsigned short* __restrict__ Wt, int Kd, int Nd,
    int tilesN, int cpx) {
  __shared__ unsigned L[64 * 33];
  int bidx = (blockIdx.x & 7) * cpx + (blockIdx.x >> 3);
  int nt = bidx % tilesN;
  int r2 = bidx / tilesN;
  int tilesK = Kd >> 6;
  int kt = r2 % tilesK;
  int e = r2 / tilesK;
  int tid = threadIdx.x;

  const float* src = W + (long)e * Kd * Nd + (long)(kt * 64) * Nd + nt * 64;
  int kp = tid >> 3;
  int nb = tid & 7;
  const float* r0 = src + (long)(2 * kp) * Nd + nb * 8;
  const float* r1 = r0 + Nd;
  float4 va0 = *(const float4*)r0;
  float4 va1 = *(const float4*)(r0 + 4);
  float4 vb0 = *(const float4*)r1;
  float4 vb1 = *(const float4*)(r1 + 4);
  const float* a = (const float*)&va0;
  const float* bq = (const float*)&vb0;
#pragma unroll
  for (int j = 0; j < 4; ++j) {
    unsigned p = (unsigned)f2b(a[j]) | ((unsigned)f2b(bq[j]) << 16);
    L[(nb * 8 + j) * 33 + kp] = p;
  }
  const float* a2 = (const float*)&va1;
  const float* b2 = (const float*)&vb1;
#pragma unroll
  for (int j = 0; j < 4; ++j) {
    unsigned p = (unsigned)f2b(a2[j]) | ((unsigned)f2b(b2[j]) << 16);
    L[(nb * 8 + 4 + j) * 33 + kp] = p;
  }
  __syncthreads();
  int n = tid >> 2;
  int part = tid & 3;
  unsigned q[8];
#pragma unroll
  for (int j = 0; j < 8; ++j) q[j] = L[n * 33 + part * 8 + j];
  unsigned* dst = (unsigned*)(Wt + (long)e * Nd * Kd + (long)(nt * 64 + n) * Kd +
                              kt * 64) +
                  part * 8;
  *(uint4*)dst = make_uint4(q[0], q[1], q[2], q[3]);
  *(uint4*)(dst + 4) = make_uint4(q[4], q[5], q[6], q[7]);
}

// ---------------- grouped GEMM (m97 structure): A[rows][K] bf16 x Bt[E][N][K] bf16 ----------------
// OMODE 0: f32 store; 1: bf16 store; 2: f32 atomicAdd of s*(acc+bias) into out[token]
template <int BN_, int WM, int WN, bool GELU, int OMODE>
__global__ __launch_bounds__(256) void gemm_bt(
    const unsigned short* __restrict__ A, int lda,
    const unsigned short* __restrict__ Bt, long strideB,
    const float* __restrict__ bias, int strideBias, void* __restrict__ Cout,
    int ldc, const int* __restrict__ row_of, const float* __restrict__ s_of,
    const int* __restrict__ tile_map, const int* __restrict__ ntiles, int N,
    int K) {
  const int nb = N / BN_;
  const int tile = blockIdx.x / nb;
  if (tile >= *ntiles) return;
  const int ct = blockIdx.x % nb;
  const int e = tile_map[tile * 4 + 0];
  const int row0 = tile_map[tile * 4 + 1];
  const int rows = tile_map[tile * 4 + 2];
  const int n0 = ct * BN_;
  const unsigned short* B_e = Bt + (long)e * strideB + (long)n0 * K;

  __shared__ __align__(16) unsigned short Asm[BM * BK];
  __shared__ __align__(16) unsigned short Bsm[BN_ * BK];

  const int tid = threadIdx.x;
  const int lane = tid & 63;
  const int w = tid >> 6;
  const int WTM = BM / WM, WTN = BN_ / WN;
  const int wr = (w / WN) * WTM;
  const int wc = (w % WN) * WTN;
  const int MR = WTM / 16, NR = WTN / 16;
  const int l15 = lane & 15;
  const int l4 = lane >> 4;

  f32x4 acc[MR][NR] = {};

  for (int k0 = 0; k0 < K; k0 += BK) {
    // A: 128x64 bf16 = 16KB -> 4 wave-wide 16B loads per thread-slot
#pragma unroll
    for (int it = 0; it < 4; ++it) {
      int c = it * 256 + tid;
      int r = c >> 3, kc = c & 7;
      int kcs = kc ^ (r & 7);
      load_lds16(A + (size_t)(row0 + r) * lda + k0 + kcs * 8,
                 ((char*)Asm) + (size_t)(it * 256 + w * 64) * 16);
    }
    // B: BN_ x 64 bf16 -> BN_/32 loads
#pragma unroll
    for (int it = 0; it < BN_ / 32; ++it) {
      int c = it * 256 + tid;
      int r = c >> 3, kc = c & 7;
      int kcs = kc ^ (r & 7);
      load_lds16(B_e + (size_t)r * K + k0 + kcs * 8,
                 ((char*)Bsm) + (size_t)(it * 256 + w * 64) * 16);
    }
    __syncthreads();
#pragma unroll
    for (int kk = 0; kk < 2; ++kk) {
      bf16x8 a[MR], b[NR];
#pragma unroll
      for (int m = 0; m < MR; ++m) {
        int row = wr + m * 16 + l15;
        int ch = (kk * 4 + l4) ^ (l15 & 7);
        a[m] = *(const bf16x8*)&Asm[row * BK + ch * 8];
      }
#pragma unroll
      for (int n = 0; n < NR; ++n) {
        int row = wc + n * 16 + l15;
        int ch = (kk * 4 + l4) ^ (l15 & 7);
        b[n] = *(const bf16x8*)&Bsm[row * BK + ch * 8];
      }
#pragma unroll
      for (int m = 0; m < MR; ++m)
#pragma unroll
        for (int n = 0; n < NR; ++n)
          acc[m][n] =
              __builtin_amdgcn_mfma_f32_16x16x32_bf16(a[m], b[n], acc[m][n], 0, 0, 0);
    }
    __syncthreads();
  }

  const float* bias_e = bias + (long)e * strideBias;
#pragma unroll
  for (int m = 0; m < MR; ++m) {
#pragma unroll
    for (int i = 0; i < 4; ++i) {
      int r = wr + m * 16 + l4 * 4 + i;
      if (r < rows) {
        if (OMODE == 2) {
          int tok = row_of[row0 + r];
          float s = s_of[row0 + r];
          float* op = (float*)Cout + (size_t)tok * ldc;
#pragma unroll
          for (int n = 0; n < NR; ++n) {
            int cg = n0 + wc + n * 16 + l15;
            float v = acc[m][n][i] + bias_e[cg];
            atomicAdd(&op[cg], s * v);
          }
        } else {
          size_t grow = (size_t)(row0 + r) * ldc;
#pragma unroll
          for (int n = 0; n < NR; ++n) {
            int cg = n0 + wc + n * 16 + l15;
            float v = acc[m][n][i] + bias_e[cg];
            if (GELU) v = gelu_fast(v);
            if (OMODE == 1)
              ((unsigned short*)Cout)[grow + cg] = f2b(v);
            else
              ((float*)Cout)[grow + cg] = v;
          }
        }
      }
    }
  }
}

extern "C" void kernel_launch(void* const* d_in, const int* in_sizes, int n_in,
                              void* d_out, int out_size, void* d_ws, size_t ws_size,
                              hipStream_t stream) {
  const float* x = (const float*)d_in[0];
  const float* gw = (const float*)d_in[1];
  const float* gb = (const float*)d_in[2];
  const float* w1 = (const float*)d_in[3];
  const float* b1 = (const float*)d_in[4];
  const float* w2 = (const float*)d_in[5];
  const float* b2 = (const float*)d_in[6];
  float* out = (float*)d_out;
  char* ws = (char*)d_ws;

  int* counts = (int*)(ws + 0);
  int* cursors = (int*)(ws + 64);
  int* ntiles = (int*)(ws + 128);
  int* offsets = (int*)(ws + 192);
  int* tile_map = (int*)(ws + 256);
  int* idx2 = (int*)(ws + 4096);
  float* sc2 = (float*)(ws + 20480);
  int* pos_of = (int*)(ws + 36864);
  int* row_of = (int*)(ws + 53248);
  float* s_of = (float*)(ws + 73728);
  unsigned short* Xp = (unsigned short*)(ws + 131072);    // 4224x1024 bf16
  unsigned short* H1 = (unsigned short*)(ws + 8781824);   // 4224x4096 bf16
  unsigned short* Wt = (unsigned short*)(ws + 43384832);  // 8x4096x1024 bf16
  if (ws_size < 110493696ULL) return;

  hipMemsetAsync(counts, 0, 64, stream);
  hipMemsetAsync(out, 0, (size_t)B_TOK * DMODEL * 4, stream);
  gate_kernel<<<B_TOK / 4, 256, 0, stream>>>(x, gw, gb, idx2, sc2, counts);
  plan_kernel<<<1, 1, 0, stream>>>(counts, offsets, tile_map, ntiles, cursors);
  scatter_kernel<<<(B_TOK * TOPK) / 256, 256, 0, stream>>>(idx2, sc2, offsets,
                                                           cursors, pos_of, row_of,
                                                           s_of);
  gather_kernel<<<B_TOK * TOPK, 256, 0, stream>>>(x, row_of, Xp);

  // w1 [E][D][H] f32 -> Wt [E][H][D] bf16  (grid 8192, cpx=1024)
  convT_kernel<<<NEXP * (DMODEL / 64) * (HDIM / 64), 256, 0, stream>>>(
      w1, Wt, DMODEL, HDIM, HDIM / 64, NEXP * (DMODEL / 64) * (HDIM / 64) / 8);
  gemm_bt<128, 2, 2, true, 1><<<MAX_TILES * (HDIM / 128), 256, 0, stream>>>(
      Xp, DMODEL, Wt, (long)HDIM * DMODEL, b1, HDIM, H1, HDIM, nullptr, nullptr,
      tile_map, ntiles, HDIM, DMODEL);
  // w2 [E][H][D] f32 -> Wt [E][D][H] bf16 (reuse buffer; grid 8192, cpx=1024)
  convT_kernel<<<NEXP * (HDIM / 64) * (DMODEL / 64), 256, 0, stream>>>(
      w2, Wt, HDIM, DMODEL, DMODEL / 64, NEXP * (HDIM / 64) * (DMODEL / 64) / 8);
  gemm_bt<64, 4, 1, false, 2><<<MAX_TILES * (DMODEL / 64), 256, 0, stream>>>(
      H1, HDIM, Wt, (long)DMODEL * HDIM, b2, DMODEL, out, DMODEL, row_of, s_of,
      tile_map, ntiles, DMODEL, HDIM);
}

// Round 10
// 275.896 us; speedup vs baseline: 1.2636x; 1.2258x over previous
//
#include <hip/hip_runtime.h>
#include <math.h>

#define B_TOK 2048
#define DMODEL 1024
#define HDIM 4096
#define NEXP 8
#define TOPK 2

#define BM 128
#define BK 64
#define MAX_TILES 40

typedef __attribute__((ext_vector_type(8))) short bf16x8;
typedef __attribute__((ext_vector_type(4))) float f32x4;

__device__ __forceinline__ unsigned short f2b(float f) {
  unsigned u = __builtin_bit_cast(unsigned, f);
  unsigned r = (u + 0x7FFFu + ((u >> 16) & 1u)) >> 16;
  return (unsigned short)r;
}

__device__ __forceinline__ void load_lds16(const void* g, void* l) {
  __builtin_amdgcn_global_load_lds(
      (const __attribute__((address_space(1))) unsigned int*)g,
      (__attribute__((address_space(3))) unsigned int*)l, 16, 0, 0);
}

// exact-gelu via branchless A&S 7.1.26 erf (|err| <= 1.5e-7, << bf16 ulp)
__device__ __forceinline__ float gelu_fast(float v) {
  float x = v * 0.70710678118654752f;
  float ax = fabsf(x);
  float t = 1.0f / (1.0f + 0.3275911f * ax);
  float e = exp2f(-ax * ax * 1.4426950408889634f);
  float p = t * (0.254829592f +
                 t * (-0.284496736f +
                      t * (1.421413741f +
                           t * (-1.453152027f + t * 1.061405429f))));
  float er = 1.0f - p * e;
  er = copysignf(er, x);
  return 0.5f * v * (1.0f + er);
}

// ------- gate: logits (f64 accum) -> top2 -> softmax; also zeroes out rows -------
__global__ __launch_bounds__(256) void gate_kernel(
    const float* __restrict__ x, const float* __restrict__ gw,
    const float* __restrict__ gb, int* __restrict__ idx2,
    float* __restrict__ sc2, float* __restrict__ out) {
  int lane = threadIdx.x & 63;
  int w = threadIdx.x >> 6;
  int b = blockIdx.x * 4 + w;
  // zero the out rows this block owns (replaces hipMemsetAsync(out))
  {
    float4 z = make_float4(0.f, 0.f, 0.f, 0.f);
    float* orow = out + (size_t)(blockIdx.x * 4) * DMODEL;
#pragma unroll
    for (int i = 0; i < 4; ++i)
      *(float4*)(orow + i * 1024 + threadIdx.x * 4) = z;
  }
  double acc[NEXP];
#pragma unroll
  for (int e = 0; e < NEXP; ++e) acc[e] = 0.0;
  const float* xr = x + (size_t)b * DMODEL;
#pragma unroll
  for (int i = 0; i < 4; ++i) {
    float4 xv = *(const float4*)(xr + i * 256 + lane * 4);
#pragma unroll
    for (int e = 0; e < NEXP; ++e) {
      float4 wv = *(const float4*)(gw + e * DMODEL + i * 256 + lane * 4);
      acc[e] += (double)xv.x * wv.x + (double)xv.y * wv.y +
                (double)xv.z * wv.z + (double)xv.w * wv.w;
    }
  }
#pragma unroll
  for (int e = 0; e < NEXP; ++e) {
    double v = acc[e];
    for (int o = 1; o < 64; o <<= 1) v += __shfl_xor(v, o, 64);
    acc[e] = v + (double)gb[e];
  }
  if (lane == 0) {
    int i0 = 0;
    double v0 = acc[0];
#pragma unroll
    for (int e = 1; e < NEXP; ++e)
      if (acc[e] > v0) { v0 = acc[e]; i0 = e; }
    int i1 = -1;
    double v1 = -1e300;
#pragma unroll
    for (int e = 0; e < NEXP; ++e)
      if (e != i0 && acc[e] > v1) { v1 = acc[e]; i1 = e; }
    double t = exp(v1 - v0);
    float s0 = (float)(1.0 / (1.0 + t));
    float s1 = (float)(t / (1.0 + t));
    idx2[b * 2] = i0;
    idx2[b * 2 + 1] = i1;
    sc2[b * 2] = s0;
    sc2[b * 2 + 1] = s1;
  }
}

// ---- route: single block; histogram + stable counting sort + tile map ----
// Replaces memset(counts) + plan + scatter. Fully deterministic.
__global__ __launch_bounds__(256) void route_kernel(
    const int* __restrict__ idx2, const float* __restrict__ sc2,
    int* __restrict__ tile_map, int* __restrict__ ntiles,
    int* __restrict__ pos_of, int* __restrict__ row_of,
    float* __restrict__ s_of) {
  __shared__ int lc[NEXP][257];  // [e][tid+1] = count in thread's 16-chunk
  __shared__ int offs[NEXP + 1];
  const int tid = threadIdx.x;
  const int base = tid * 16;  // 256*16 = 4096 slots
#pragma unroll
  for (int e = 0; e < NEXP; ++e) lc[e][tid + 1] = 0;
  if (tid < NEXP) lc[tid][0] = 0;
  __syncthreads();
  int loc[16];
#pragma unroll
  for (int j = 0; j < 16; ++j) {
    int e = idx2[base + j];
    loc[j] = e;
    atomicAdd(&lc[e][tid + 1], 1);  // LDS atomic, own column
  }
  __syncthreads();
  // per-expert serial prefix over 256 thread-chunks (8 threads)
  if (tid < NEXP) {
    int s = 0;
    for (int i = 1; i <= 256; ++i) {
      s += lc[tid][i];
      lc[tid][i] = s;  // inclusive through chunk i-1
    }
  }
  __syncthreads();
  if (tid == 0) {
    offs[0] = 0;
    for (int e = 0; e < NEXP; ++e) offs[e + 1] = offs[e] + lc[e][256];
    int tt = 0;
    for (int e = 0; e < NEXP; ++e) {
      int cnt = lc[e][256];
      int bse = offs[e];
      for (int t = 0; t * BM < cnt; ++t) {
        tile_map[tt * 4 + 0] = e;
        tile_map[tt * 4 + 1] = bse + t * BM;
        tile_map[tt * 4 + 2] = (cnt - t * BM) < BM ? (cnt - t * BM) : BM;
        tile_map[tt * 4 + 3] = 0;
        ++tt;
      }
    }
    *ntiles = tt;
  }
  __syncthreads();
  // exclusive base for this thread per expert, then stable placement
#pragma unroll
  for (int e = 0; e < NEXP; ++e) lc[e][tid] += offs[e];
  __syncthreads();  // (only own column read below; barrier for offs visibility)
#pragma unroll
  for (int j = 0; j < 16; ++j) {
    int e = loc[j];
    int p = lc[e][tid];
    lc[e][tid] = p + 1;  // own column, no race
    int t = base + j;
    pos_of[t] = p;
    row_of[p] = t >> 1;
    s_of[p] = sc2[t];
  }
}

// ---------------- gather: permuted bf16 activations ----------------
__global__ __launch_bounds__(256) void gather_kernel(
    const float* __restrict__ x, const int* __restrict__ row_of,
    unsigned short* __restrict__ Xp) {
  int r = blockIdx.x;
  int tok = row_of[r];
  int c = threadIdx.x * 4;
  float4 v = *(const float4*)(x + (size_t)tok * DMODEL + c);
  ushort4 o = make_ushort4(f2b(v.x), f2b(v.y), f2b(v.z), f2b(v.w));
  *(ushort4*)(Xp + (size_t)r * DMODEL + c) = o;
}

// ---- transpose+convert: W[e][k][n] f32 -> Wt[e][n][k] bf16 (u32 k-pair pack) ----
// 64x64 tile. Write/read LDS banks both exactly 2-way (stride 33 words).
// XCD-swizzled block remap (bijective, grid%8==0): same-row tiles share an XCD L2.
__global__ __launch_bounds__(256) void convT_kernel(
    const float* __restrict__ W, unsigned short* __restrict__ Wt, int Kd, int Nd,
    int tilesN, int cpx) {
  __shared__ unsigned L[64 * 33];
  int bidx = (blockIdx.x & 7) * cpx + (blockIdx.x >> 3);
  int nt = bidx % tilesN;
  int r2 = bidx / tilesN;
  int tilesK = Kd >> 6;
  int kt = r2 % tilesK;
  int e = r2 / tilesK;
  int tid = threadIdx.x;

  const float* src = W + (long)e * Kd * Nd + (long)(kt * 64) * Nd + nt * 64;
  int kp = tid >> 3;
  int nb = tid & 7;
  const float* r0 = src + (long)(2 * kp) * Nd + nb * 8;
  const float* r1 = r0 + Nd;
  float4 va0 = *(const float4*)r0;
  float4 va1 = *(const float4*)(r0 + 4);
  float4 vb0 = *(const float4*)r1;
  float4 vb1 = *(const float4*)(r1 + 4);
  const float* a = (const float*)&va0;
  const float* bq = (const float*)&vb0;
#pragma unroll
  for (int j = 0; j < 4; ++j) {
    unsigned p = (unsigned)f2b(a[j]) | ((unsigned)f2b(bq[j]) << 16);
    L[(nb * 8 + j) * 33 + kp] = p;
  }
  const float* a2 = (const float*)&va1;
  const float* b2 = (const float*)&vb1;
#pragma unroll
  for (int j = 0; j < 4; ++j) {
    unsigned p = (unsigned)f2b(a2[j]) | ((unsigned)f2b(b2[j]) << 16);
    L[(nb * 8 + 4 + j) * 33 + kp] = p;
  }
  __syncthreads();
  int n = tid >> 2;
  int part = tid & 3;
  unsigned q[8];
#pragma unroll
  for (int j = 0; j < 8; ++j) q[j] = L[n * 33 + part * 8 + j];
  unsigned* dst = (unsigned*)(Wt + (long)e * Nd * Kd + (long)(nt * 64 + n) * Kd +
                              kt * 64) +
                  part * 8;
  *(uint4*)dst = make_uint4(q[0], q[1], q[2], q[3]);
  *(uint4*)(dst + 4) = make_uint4(q[4], q[5], q[6], q[7]);
}

// ---------------- grouped GEMM (m97 structure): A[rows][K] bf16 x Bt[E][N][K] bf16 ----------------
// OMODE 0: f32 store; 1: bf16 store; 2: f32 atomicAdd of s*(acc+bias) into out[token]
template <int BN_, int WM, int WN, bool GELU, int OMODE>
__global__ __launch_bounds__(256) void gemm_bt(
    const unsigned short* __restrict__ A, int lda,
    const unsigned short* __restrict__ Bt, long strideB,
    const float* __restrict__ bias, int strideBias, void* __restrict__ Cout,
    int ldc, const int* __restrict__ row_of, const float* __restrict__ s_of,
    const int* __restrict__ tile_map, const int* __restrict__ ntiles, int N,
    int K) {
  const int nb = N / BN_;
  const int tile = blockIdx.x / nb;
  if (tile >= *ntiles) return;
  const int ct = blockIdx.x % nb;
  const int e = tile_map[tile * 4 + 0];
  const int row0 = tile_map[tile * 4 + 1];
  const int rows = tile_map[tile * 4 + 2];
  const int n0 = ct * BN_;
  const unsigned short* B_e = Bt + (long)e * strideB + (long)n0 * K;

  __shared__ __align__(16) unsigned short Asm[BM * BK];
  __shared__ __align__(16) unsigned short Bsm[BN_ * BK];

  const int tid = threadIdx.x;
  const int lane = tid & 63;
  const int w = tid >> 6;
  const int WTM = BM / WM, WTN = BN_ / WN;
  const int wr = (w / WN) * WTM;
  const int wc = (w % WN) * WTN;
  const int MR = WTM / 16, NR = WTN / 16;
  const int l15 = lane & 15;
  const int l4 = lane >> 4;

  f32x4 acc[MR][NR] = {};

  for (int k0 = 0; k0 < K; k0 += BK) {
    // A: 128x64 bf16 = 16KB -> 4 wave-wide 16B loads per thread-slot
#pragma unroll
    for (int it = 0; it < 4; ++it) {
      int c = it * 256 + tid;
      int r = c >> 3, kc = c & 7;
      int kcs = kc ^ (r & 7);
      load_lds16(A + (size_t)(row0 + r) * lda + k0 + kcs * 8,
                 ((char*)Asm) + (size_t)(it * 256 + w * 64) * 16);
    }
    // B: BN_ x 64 bf16 -> BN_/32 loads
#pragma unroll
    for (int it = 0; it < BN_ / 32; ++it) {
      int c = it * 256 + tid;
      int r = c >> 3, kc = c & 7;
      int kcs = kc ^ (r & 7);
      load_lds16(B_e + (size_t)r * K + k0 + kcs * 8,
                 ((char*)Bsm) + (size_t)(it * 256 + w * 64) * 16);
    }
    __syncthreads();
#pragma unroll
    for (int kk = 0; kk < 2; ++kk) {
      bf16x8 a[MR], b[NR];
#pragma unroll
      for (int m = 0; m < MR; ++m) {
        int row = wr + m * 16 + l15;
        int ch = (kk * 4 + l4) ^ (l15 & 7);
        a[m] = *(const bf16x8*)&Asm[row * BK + ch * 8];
      }
#pragma unroll
      for (int n = 0; n < NR; ++n) {
        int row = wc + n * 16 + l15;
        int ch = (kk * 4 + l4) ^ (l15 & 7);
        b[n] = *(const bf16x8*)&Bsm[row * BK + ch * 8];
      }
#pragma unroll
      for (int m = 0; m < MR; ++m)
#pragma unroll
        for (int n = 0; n < NR; ++n)
          acc[m][n] =
              __builtin_amdgcn_mfma_f32_16x16x32_bf16(a[m], b[n], acc[m][n], 0, 0, 0);
    }
    __syncthreads();
  }

  const float* bias_e = bias + (long)e * strideBias;
#pragma unroll
  for (int m = 0; m < MR; ++m) {
#pragma unroll
    for (int i = 0; i < 4; ++i) {
      int r = wr + m * 16 + l4 * 4 + i;
      if (r < rows) {
        if (OMODE == 2) {
          int tok = row_of[row0 + r];
          float s = s_of[row0 + r];
          float* op = (float*)Cout + (size_t)tok * ldc;
#pragma unroll
          for (int n = 0; n < NR; ++n) {
            int cg = n0 + wc + n * 16 + l15;
            float v = acc[m][n][i] + bias_e[cg];
            atomicAdd(&op[cg], s * v);
          }
        } else {
          size_t grow = (size_t)(row0 + r) * ldc;
#pragma unroll
          for (int n = 0; n < NR; ++n) {
            int cg = n0 + wc + n * 16 + l15;
            float v = acc[m][n][i] + bias_e[cg];
            if (GELU) v = gelu_fast(v);
            if (OMODE == 1)
              ((unsigned short*)Cout)[grow + cg] = f2b(v);
            else
              ((float*)Cout)[grow + cg] = v;
          }
        }
      }
    }
  }
}

extern "C" void kernel_launch(void* const* d_in, const int* in_sizes, int n_in,
                              void* d_out, int out_size, void* d_ws, size_t ws_size,
                              hipStream_t stream) {
  const float* x = (const float*)d_in[0];
  const float* gw = (const float*)d_in[1];
  const float* gb = (const float*)d_in[2];
  const float* w1 = (const float*)d_in[3];
  const float* b1 = (const float*)d_in[4];
  const float* w2 = (const float*)d_in[5];
  const float* b2 = (const float*)d_in[6];
  float* out = (float*)d_out;
  char* ws = (char*)d_ws;

  int* ntiles = (int*)(ws + 128);
  int* tile_map = (int*)(ws + 256);
  int* idx2 = (int*)(ws + 4096);
  float* sc2 = (float*)(ws + 20480);
  int* pos_of = (int*)(ws + 36864);
  int* row_of = (int*)(ws + 53248);
  float* s_of = (float*)(ws + 73728);
  unsigned short* Xp = (unsigned short*)(ws + 131072);    // 4224x1024 bf16
  unsigned short* H1 = (unsigned short*)(ws + 8781824);   // 4224x4096 bf16
  unsigned short* Wt = (unsigned short*)(ws + 43384832);  // 8x4096x1024 bf16
  if (ws_size < 110493696ULL) return;

  // gate also zeroes `out` (for GEMM2's atomic combine)
  gate_kernel<<<B_TOK / 4, 256, 0, stream>>>(x, gw, gb, idx2, sc2, out);
  route_kernel<<<1, 256, 0, stream>>>(idx2, sc2, tile_map, ntiles, pos_of,
                                      row_of, s_of);
  gather_kernel<<<B_TOK * TOPK, 256, 0, stream>>>(x, row_of, Xp);

  // w1 [E][D][H] f32 -> Wt [E][H][D] bf16  (grid 8192, cpx=1024)
  convT_kernel<<<NEXP * (DMODEL / 64) * (HDIM / 64), 256, 0, stream>>>(
      w1, Wt, DMODEL, HDIM, HDIM / 64, NEXP * (DMODEL / 64) * (HDIM / 64) / 8);
  gemm_bt<128, 2, 2, true, 1><<<MAX_TILES * (HDIM / 128), 256, 0, stream>>>(
      Xp, DMODEL, Wt, (long)HDIM * DMODEL, b1, HDIM, H1, HDIM, nullptr, nullptr,
      tile_map, ntiles, HDIM, DMODEL);
  // w2 [E][H][D] f32 -> Wt [E][D][H] bf16 (reuse buffer; grid 8192, cpx=1024)
  convT_kernel<<<NEXP * (HDIM / 64) * (DMODEL / 64), 256, 0, stream>>>(
      w2, Wt, HDIM, DMODEL, DMODEL / 64, NEXP * (HDIM / 64) * (DMODEL / 64) / 8);
  gemm_bt<64, 4, 1, false, 2><<<MAX_TILES * (DMODEL / 64), 256, 0, stream>>>(
      H1, HDIM, Wt, (long)DMODEL * HDIM, b2, DMODEL, out, DMODEL, row_of, s_of,
      tile_map, ntiles, DMODEL, HDIM);
}

// Round 11
// 270.256 us; speedup vs baseline: 1.2899x; 1.0209x over previous
//
#include <hip/hip_runtime.h>
#include <math.h>

#define B_TOK 2048
#define DMODEL 1024
#define HDIM 4096
#define NEXP 8
#define TOPK 2

#define BM 128
#define BK 64
#define MAX_TILES 40
#define MAX_T256 24

typedef __attribute__((ext_vector_type(8))) short bf16x8;
typedef __attribute__((ext_vector_type(4))) float f32x4;

__device__ __forceinline__ unsigned short f2b(float f) {
  unsigned u = __builtin_bit_cast(unsigned, f);
  unsigned r = (u + 0x7FFFu + ((u >> 16) & 1u)) >> 16;
  return (unsigned short)r;
}

__device__ __forceinline__ void load_lds16(const void* g, void* l) {
  __builtin_amdgcn_global_load_lds(
      (const __attribute__((address_space(1))) unsigned int*)g,
      (__attribute__((address_space(3))) unsigned int*)l, 16, 0, 0);
}

// exact-gelu via branchless A&S 7.1.26 erf (|err| <= 1.5e-7, << bf16 ulp)
__device__ __forceinline__ float gelu_fast(float v) {
  float x = v * 0.70710678118654752f;
  float ax = fabsf(x);
  float t = 1.0f / (1.0f + 0.3275911f * ax);
  float e = exp2f(-ax * ax * 1.4426950408889634f);
  float p = t * (0.254829592f +
                 t * (-0.284496736f +
                      t * (1.421413741f +
                           t * (-1.453152027f + t * 1.061405429f))));
  float er = 1.0f - p * e;
  er = copysignf(er, x);
  return 0.5f * v * (1.0f + er);
}

// ------- gate: logits (f64 accum) -> top2 -> softmax; also zeroes out rows -------
__global__ __launch_bounds__(256) void gate_kernel(
    const float* __restrict__ x, const float* __restrict__ gw,
    const float* __restrict__ gb, int* __restrict__ idx2,
    float* __restrict__ sc2, float* __restrict__ out) {
  int lane = threadIdx.x & 63;
  int w = threadIdx.x >> 6;
  int b = blockIdx.x * 4 + w;
  {
    float4 z = make_float4(0.f, 0.f, 0.f, 0.f);
    float* orow = out + (size_t)(blockIdx.x * 4) * DMODEL;
#pragma unroll
    for (int i = 0; i < 4; ++i)
      *(float4*)(orow + i * 1024 + threadIdx.x * 4) = z;
  }
  double acc[NEXP];
#pragma unroll
  for (int e = 0; e < NEXP; ++e) acc[e] = 0.0;
  const float* xr = x + (size_t)b * DMODEL;
#pragma unroll
  for (int i = 0; i < 4; ++i) {
    float4 xv = *(const float4*)(xr + i * 256 + lane * 4);
#pragma unroll
    for (int e = 0; e < NEXP; ++e) {
      float4 wv = *(const float4*)(gw + e * DMODEL + i * 256 + lane * 4);
      acc[e] += (double)xv.x * wv.x + (double)xv.y * wv.y +
                (double)xv.z * wv.z + (double)xv.w * wv.w;
    }
  }
#pragma unroll
  for (int e = 0; e < NEXP; ++e) {
    double v = acc[e];
    for (int o = 1; o < 64; o <<= 1) v += __shfl_xor(v, o, 64);
    acc[e] = v + (double)gb[e];
  }
  if (lane == 0) {
    int i0 = 0;
    double v0 = acc[0];
#pragma unroll
    for (int e = 1; e < NEXP; ++e)
      if (acc[e] > v0) { v0 = acc[e]; i0 = e; }
    int i1 = -1;
    double v1 = -1e300;
#pragma unroll
    for (int e = 0; e < NEXP; ++e)
      if (e != i0 && acc[e] > v1) { v1 = acc[e]; i1 = e; }
    double t = exp(v1 - v0);
    float s0 = (float)(1.0 / (1.0 + t));
    float s1 = (float)(t / (1.0 + t));
    idx2[b * 2] = i0;
    idx2[b * 2 + 1] = i1;
    sc2[b * 2] = s0;
    sc2[b * 2 + 1] = s1;
  }
}

// ---- route: single block; histogram + stable counting sort + BOTH tile maps ----
__global__ __launch_bounds__(256) void route_kernel(
    const int* __restrict__ idx2, const float* __restrict__ sc2,
    int* __restrict__ tile_map, int* __restrict__ ntiles,
    int* __restrict__ tm256, int* __restrict__ nt256,
    int* __restrict__ pos_of, int* __restrict__ row_of,
    float* __restrict__ s_of) {
  __shared__ int lc[NEXP][257];
  __shared__ int offs[NEXP + 1];
  const int tid = threadIdx.x;
  const int base = tid * 16;
#pragma unroll
  for (int e = 0; e < NEXP; ++e) lc[e][tid + 1] = 0;
  if (tid < NEXP) lc[tid][0] = 0;
  __syncthreads();
  int loc[16];
#pragma unroll
  for (int j = 0; j < 16; ++j) {
    int e = idx2[base + j];
    loc[j] = e;
    atomicAdd(&lc[e][tid + 1], 1);
  }
  __syncthreads();
  if (tid < NEXP) {
    int s = 0;
    for (int i = 1; i <= 256; ++i) {
      s += lc[tid][i];
      lc[tid][i] = s;
    }
  }
  __syncthreads();
  if (tid == 0) {
    offs[0] = 0;
    for (int e = 0; e < NEXP; ++e) offs[e + 1] = offs[e] + lc[e][256];
    int tt = 0, t2 = 0;
    for (int e = 0; e < NEXP; ++e) {
      int cnt = lc[e][256];
      int bse = offs[e];
      for (int t = 0; t * BM < cnt; ++t) {
        tile_map[tt * 4 + 0] = e;
        tile_map[tt * 4 + 1] = bse + t * BM;
        tile_map[tt * 4 + 2] = (cnt - t * BM) < BM ? (cnt - t * BM) : BM;
        tile_map[tt * 4 + 3] = 0;
        ++tt;
      }
      for (int t = 0; t * 256 < cnt; ++t) {
        tm256[t2 * 4 + 0] = e;
        tm256[t2 * 4 + 1] = bse + t * 256;
        tm256[t2 * 4 + 2] = (cnt - t * 256) < 256 ? (cnt - t * 256) : 256;
        tm256[t2 * 4 + 3] = 0;
        ++t2;
      }
    }
    *ntiles = tt;
    *nt256 = t2;
  }
  __syncthreads();
#pragma unroll
  for (int e = 0; e < NEXP; ++e) lc[e][tid] += offs[e];
  __syncthreads();
#pragma unroll
  for (int j = 0; j < 16; ++j) {
    int e = loc[j];
    int p = lc[e][tid];
    lc[e][tid] = p + 1;
    int t = base + j;
    pos_of[t] = p;
    row_of[p] = t >> 1;
    s_of[p] = sc2[t];
  }
}

// ---------------- gather: permuted bf16 activations ----------------
__global__ __launch_bounds__(256) void gather_kernel(
    const float* __restrict__ x, const int* __restrict__ row_of,
    unsigned short* __restrict__ Xp) {
  int r = blockIdx.x;
  int tok = row_of[r];
  int c = threadIdx.x * 4;
  float4 v = *(const float4*)(x + (size_t)tok * DMODEL + c);
  ushort4 o = make_ushort4(f2b(v.x), f2b(v.y), f2b(v.z), f2b(v.w));
  *(ushort4*)(Xp + (size_t)r * DMODEL + c) = o;
}

// ---- transpose+convert: W[e][k][n] f32 -> Wt[e][n][k] bf16 (u32 k-pair pack) ----
__global__ __launch_bounds__(256) void convT_kernel(
    const float* __restrict__ W, unsigned short* __restrict__ Wt, int Kd, int Nd,
    int tilesN, int cpx) {
  __shared__ unsigned L[64 * 33];
  int bidx = (blockIdx.x & 7) * cpx + (blockIdx.x >> 3);
  int nt = bidx % tilesN;
  int r2 = bidx / tilesN;
  int tilesK = Kd >> 6;
  int kt = r2 % tilesK;
  int e = r2 / tilesK;
  int tid = threadIdx.x;

  const float* src = W + (long)e * Kd * Nd + (long)(kt * 64) * Nd + nt * 64;
  int kp = tid >> 3;
  int nb = tid & 7;
  const float* r0 = src + (long)(2 * kp) * Nd + nb * 8;
  const float* r1 = r0 + Nd;
  float4 va0 = *(const float4*)r0;
  float4 va1 = *(const float4*)(r0 + 4);
  float4 vb0 = *(const float4*)r1;
  float4 vb1 = *(const float4*)(r1 + 4);
  const float* a = (const float*)&va0;
  const float* bq = (const float*)&vb0;
#pragma unroll
  for (int j = 0; j < 4; ++j) {
    unsigned p = (unsigned)f2b(a[j]) | ((unsigned)f2b(bq[j]) << 16);
    L[(nb * 8 + j) * 33 + kp] = p;
  }
  const float* a2 = (const float*)&va1;
  const float* b2 = (const float*)&vb1;
#pragma unroll
  for (int j = 0; j < 4; ++j) {
    unsigned p = (unsigned)f2b(a2[j]) | ((unsigned)f2b(b2[j]) << 16);
    L[(nb * 8 + 4 + j) * 33 + kp] = p;
  }
  __syncthreads();
  int n = tid >> 2;
  int part = tid & 3;
  unsigned q[8];
#pragma unroll
  for (int j = 0; j < 8; ++j) q[j] = L[n * 33 + part * 8 + j];
  unsigned* dst = (unsigned*)(Wt + (long)e * Nd * Kd + (long)(nt * 64 + n) * Kd +
                              kt * 64) +
                  part * 8;
  *(uint4*)dst = make_uint4(q[0], q[1], q[2], q[3]);
  *(uint4*)(dst + 4) = make_uint4(q[4], q[5], q[6], q[7]);
}

// ------- G1: 256x128 tile, 512 threads (8 waves 4Mx2N), single-buffer -------
// Intensity 85 FLOP/staged-byte (vs 52.5 at 128x128): staging-ceiling ~574 TF.
// Per-wave shape identical to proven kernel (MR=4, NR=4).
__global__ __launch_bounds__(512) void gemm1_wide(
    const unsigned short* __restrict__ A, int lda,
    const unsigned short* __restrict__ Bt, long strideB,
    const float* __restrict__ bias, unsigned short* __restrict__ Cout, int ldc,
    const int* __restrict__ tm256, const int* __restrict__ nt256, int N,
    int K) {
  const int nb = N / 128;
  const int tile = blockIdx.x / nb;
  if (tile >= *nt256) return;
  const int ct = blockIdx.x % nb;
  const int e = tm256[tile * 4 + 0];
  const int row0 = tm256[tile * 4 + 1];
  const int rows = tm256[tile * 4 + 2];
  const int n0 = ct * 128;
  const unsigned short* B_e = Bt + (long)e * strideB + (long)n0 * K;

  __shared__ __align__(16) unsigned short Asm[256 * BK];
  __shared__ __align__(16) unsigned short Bsm[128 * BK];

  const int tid = threadIdx.x;
  const int lane = tid & 63;
  const int w = tid >> 6;
  const int wr = (w >> 1) * 64;  // 4 wave-rows x 64
  const int wc = (w & 1) * 64;   // 2 wave-cols x 64
  const int l15 = lane & 15;
  const int l4 = lane >> 4;

  f32x4 acc[4][4] = {};

  for (int k0 = 0; k0 < K; k0 += BK) {
    // A: 256x64 = 2048 slots of 16B -> 4 iters of 512 threads
#pragma unroll
    for (int it = 0; it < 4; ++it) {
      int c = it * 512 + tid;
      int r = c >> 3, kc = c & 7;
      int kcs = kc ^ (r & 7);
      load_lds16(A + (size_t)(row0 + r) * lda + k0 + kcs * 8,
                 ((char*)Asm) + (size_t)(it * 512 + w * 64) * 16);
    }
    // B: 128x64 = 1024 slots -> 2 iters
#pragma unroll
    for (int it = 0; it < 2; ++it) {
      int c = it * 512 + tid;
      int r = c >> 3, kc = c & 7;
      int kcs = kc ^ (r & 7);
      load_lds16(B_e + (size_t)r * K + k0 + kcs * 8,
                 ((char*)Bsm) + (size_t)(it * 512 + w * 64) * 16);
    }
    __syncthreads();
#pragma unroll
    for (int kk = 0; kk < 2; ++kk) {
      bf16x8 a[4], b[4];
#pragma unroll
      for (int m = 0; m < 4; ++m) {
        int row = wr + m * 16 + l15;
        int ch = (kk * 4 + l4) ^ (l15 & 7);
        a[m] = *(const bf16x8*)&Asm[row * BK + ch * 8];
      }
#pragma unroll
      for (int n = 0; n < 4; ++n) {
        int row = wc + n * 16 + l15;
        int ch = (kk * 4 + l4) ^ (l15 & 7);
        b[n] = *(const bf16x8*)&Bsm[row * BK + ch * 8];
      }
#pragma unroll
      for (int m = 0; m < 4; ++m)
#pragma unroll
        for (int n = 0; n < 4; ++n)
          acc[m][n] =
              __builtin_amdgcn_mfma_f32_16x16x32_bf16(a[m], b[n], acc[m][n], 0, 0, 0);
    }
    __syncthreads();
  }

  const float* bias_e = bias + (long)e * HDIM;
#pragma unroll
  for (int m = 0; m < 4; ++m) {
#pragma unroll
    for (int i = 0; i < 4; ++i) {
      int r = wr + m * 16 + l4 * 4 + i;
      if (r < rows) {
        size_t grow = (size_t)(row0 + r) * ldc;
#pragma unroll
        for (int n = 0; n < 4; ++n) {
          int cg = n0 + wc + n * 16 + l15;
          float v = acc[m][n][i] + bias_e[cg];
          v = gelu_fast(v);
          Cout[grow + cg] = f2b(v);
        }
      }
    }
  }
}

// ---------------- grouped GEMM (m97 structure): A[rows][K] bf16 x Bt[E][N][K] bf16 ----------------
// OMODE 0: f32 store; 1: bf16 store; 2: f32 atomicAdd of s*(acc+bias) into out[token]
template <int BN_, int WM, int WN, bool GELU, int OMODE>
__global__ __launch_bounds__(256) void gemm_bt(
    const unsigned short* __restrict__ A, int lda,
    const unsigned short* __restrict__ Bt, long strideB,
    const float* __restrict__ bias, int strideBias, void* __restrict__ Cout,
    int ldc, const int* __restrict__ row_of, const float* __restrict__ s_of,
    const int* __restrict__ tile_map, const int* __restrict__ ntiles, int N,
    int K) {
  const int nb = N / BN_;
  const int tile = blockIdx.x / nb;
  if (tile >= *ntiles) return;
  const int ct = blockIdx.x % nb;
  const int e = tile_map[tile * 4 + 0];
  const int row0 = tile_map[tile * 4 + 1];
  const int rows = tile_map[tile * 4 + 2];
  const int n0 = ct * BN_;
  const unsigned short* B_e = Bt + (long)e * strideB + (long)n0 * K;

  __shared__ __align__(16) unsigned short Asm[BM * BK];
  __shared__ __align__(16) unsigned short Bsm[BN_ * BK];

  const int tid = threadIdx.x;
  const int lane = tid & 63;
  const int w = tid >> 6;
  const int WTM = BM / WM, WTN = BN_ / WN;
  const int wr = (w / WN) * WTM;
  const int wc = (w % WN) * WTN;
  const int MR = WTM / 16, NR = WTN / 16;
  const int l15 = lane & 15;
  const int l4 = lane >> 4;

  f32x4 acc[MR][NR] = {};

  for (int k0 = 0; k0 < K; k0 += BK) {
#pragma unroll
    for (int it = 0; it < 4; ++it) {
      int c = it * 256 + tid;
      int r = c >> 3, kc = c & 7;
      int kcs = kc ^ (r & 7);
      load_lds16(A + (size_t)(row0 + r) * lda + k0 + kcs * 8,
                 ((char*)Asm) + (size_t)(it * 256 + w * 64) * 16);
    }
#pragma unroll
    for (int it = 0; it < BN_ / 32; ++it) {
      int c = it * 256 + tid;
      int r = c >> 3, kc = c & 7;
      int kcs = kc ^ (r & 7);
      load_lds16(B_e + (size_t)r * K + k0 + kcs * 8,
                 ((char*)Bsm) + (size_t)(it * 256 + w * 64) * 16);
    }
    __syncthreads();
#pragma unroll
    for (int kk = 0; kk < 2; ++kk) {
      bf16x8 a[MR], b[NR];
#pragma unroll
      for (int m = 0; m < MR; ++m) {
        int row = wr + m * 16 + l15;
        int ch = (kk * 4 + l4) ^ (l15 & 7);
        a[m] = *(const bf16x8*)&Asm[row * BK + ch * 8];
      }
#pragma unroll
      for (int n = 0; n < NR; ++n) {
        int row = wc + n * 16 + l15;
        int ch = (kk * 4 + l4) ^ (l15 & 7);
        b[n] = *(const bf16x8*)&Bsm[row * BK + ch * 8];
      }
#pragma unroll
      for (int m = 0; m < MR; ++m)
#pragma unroll
        for (int n = 0; n < NR; ++n)
          acc[m][n] =
              __builtin_amdgcn_mfma_f32_16x16x32_bf16(a[m], b[n], acc[m][n], 0, 0, 0);
    }
    __syncthreads();
  }

  const float* bias_e = bias + (long)e * strideBias;
#pragma unroll
  for (int m = 0; m < MR; ++m) {
#pragma unroll
    for (int i = 0; i < 4; ++i) {
      int r = wr + m * 16 + l4 * 4 + i;
      if (r < rows) {
        if (OMODE == 2) {
          int tok = row_of[row0 + r];
          float s = s_of[row0 + r];
          float* op = (float*)Cout + (size_t)tok * ldc;
#pragma unroll
          for (int n = 0; n < NR; ++n) {
            int cg = n0 + wc + n * 16 + l15;
            float v = acc[m][n][i] + bias_e[cg];
            atomicAdd(&op[cg], s * v);
          }
        } else {
          size_t grow = (size_t)(row0 + r) * ldc;
#pragma unroll
          for (int n = 0; n < NR; ++n) {
            int cg = n0 + wc + n * 16 + l15;
            float v = acc[m][n][i] + bias_e[cg];
            if (GELU) v = gelu_fast(v);
            if (OMODE == 1)
              ((unsigned short*)Cout)[grow + cg] = f2b(v);
            else
              ((float*)Cout)[grow + cg] = v;
          }
        }
      }
    }
  }
}

extern "C" void kernel_launch(void* const* d_in, const int* in_sizes, int n_in,
                              void* d_out, int out_size, void* d_ws, size_t ws_size,
                              hipStream_t stream) {
  const float* x = (const float*)d_in[0];
  const float* gw = (const float*)d_in[1];
  const float* gb = (const float*)d_in[2];
  const float* w1 = (const float*)d_in[3];
  const float* b1 = (const float*)d_in[4];
  const float* w2 = (const float*)d_in[5];
  const float* b2 = (const float*)d_in[6];
  float* out = (float*)d_out;
  char* ws = (char*)d_ws;

  int* ntiles = (int*)(ws + 128);
  int* nt256 = (int*)(ws + 132);
  int* tile_map = (int*)(ws + 256);
  int* tm256 = (int*)(ws + 2048);
  int* idx2 = (int*)(ws + 4096);
  float* sc2 = (float*)(ws + 20480);
  int* pos_of = (int*)(ws + 36864);
  int* row_of = (int*)(ws + 53248);
  float* s_of = (float*)(ws + 73728);
  unsigned short* Xp = (unsigned short*)(ws + 131072);    // 4224x1024 bf16
  unsigned short* H1 = (unsigned short*)(ws + 8781824);   // 4224x4096 bf16
  unsigned short* Wt = (unsigned short*)(ws + 43384832);  // 8x4096x1024 bf16
  if (ws_size < 110493696ULL) return;

  // keep the round-9 instantiation pair alive for codegen stability (rule #19)
  (void)&gemm_bt<128, 2, 2, true, 1>;

  gate_kernel<<<B_TOK / 4, 256, 0, stream>>>(x, gw, gb, idx2, sc2, out);
  route_kernel<<<1, 256, 0, stream>>>(idx2, sc2, tile_map, ntiles, tm256, nt256,
                                      pos_of, row_of, s_of);
  gather_kernel<<<B_TOK * TOPK, 256, 0, stream>>>(x, row_of, Xp);

  // w1 [E][D][H] f32 -> Wt [E][H][D] bf16  (grid 8192, cpx=1024)
  convT_kernel<<<NEXP * (DMODEL / 64) * (HDIM / 64), 256, 0, stream>>>(
      w1, Wt, DMODEL, HDIM, HDIM / 64, NEXP * (DMODEL / 64) * (HDIM / 64) / 8);
  // G1: 256x128 wide tile (85 FLOP/staged-byte)
  gemm1_wide<<<MAX_T256 * (HDIM / 128), 512, 0, stream>>>(
      Xp, DMODEL, Wt, (long)HDIM * DMODEL, b1, H1, HDIM, tm256, nt256, HDIM,
      DMODEL);
  // w2 [E][H][D] f32 -> Wt [E][D][H] bf16 (reuse buffer; grid 8192, cpx=1024)
  convT_kernel<<<NEXP * (HDIM / 64) * (DMODEL / 64), 256, 0, stream>>>(
      w2, Wt, HDIM, DMODEL, DMODEL / 64, NEXP * (HDIM / 64) * (DMODEL / 64) / 8);
  gemm_bt<64, 4, 1, false, 2><<<MAX_TILES * (DMODEL / 64), 256, 0, stream>>>(
      H1, HDIM, Wt, (long)DMODEL * HDIM, b2, DMODEL, out, DMODEL, row_of, s_of,
      tile_map, ntiles, DMODEL, HDIM);
}

// Round 12
// 269.304 us; speedup vs baseline: 1.2945x; 1.0035x over previous
//
#include <hip/hip_runtime.h>
#include <math.h>

#define B_TOK 2048
#define DMODEL 1024
#define HDIM 4096
#define NEXP 8
#define TOPK 2

#define BM 128
#define BK 64
#define MAX_TILES 40
#define MAX_T256 24

typedef __attribute__((ext_vector_type(8))) short bf16x8;
typedef __attribute__((ext_vector_type(4))) float f32x4;

__device__ __forceinline__ unsigned short f2b(float f) {
  unsigned u = __builtin_bit_cast(unsigned, f);
  unsigned r = (u + 0x7FFFu + ((u >> 16) & 1u)) >> 16;
  return (unsigned short)r;
}

__device__ __forceinline__ void load_lds16(const void* g, void* l) {
  __builtin_amdgcn_global_load_lds(
      (const __attribute__((address_space(1))) unsigned int*)g,
      (__attribute__((address_space(3))) unsigned int*)l, 16, 0, 0);
}

// exact-gelu via branchless A&S 7.1.26 erf (|err| <= 1.5e-7, << bf16 ulp)
__device__ __forceinline__ float gelu_fast(float v) {
  float x = v * 0.70710678118654752f;
  float ax = fabsf(x);
  float t = 1.0f / (1.0f + 0.3275911f * ax);
  float e = exp2f(-ax * ax * 1.4426950408889634f);
  float p = t * (0.254829592f +
                 t * (-0.284496736f +
                      t * (1.421413741f +
                           t * (-1.453152027f + t * 1.061405429f))));
  float er = 1.0f - p * e;
  er = copysignf(er, x);
  return 0.5f * v * (1.0f + er);
}

// ------- gate: logits (f64 accum) -> top2 -> softmax; also zeroes out rows -------
__global__ __launch_bounds__(256) void gate_kernel(
    const float* __restrict__ x, const float* __restrict__ gw,
    const float* __restrict__ gb, int* __restrict__ idx2,
    float* __restrict__ sc2, float* __restrict__ out) {
  int lane = threadIdx.x & 63;
  int w = threadIdx.x >> 6;
  int b = blockIdx.x * 4 + w;
  {
    float4 z = make_float4(0.f, 0.f, 0.f, 0.f);
    float* orow = out + (size_t)(blockIdx.x * 4) * DMODEL;
#pragma unroll
    for (int i = 0; i < 4; ++i)
      *(float4*)(orow + i * 1024 + threadIdx.x * 4) = z;
  }
  double acc[NEXP];
#pragma unroll
  for (int e = 0; e < NEXP; ++e) acc[e] = 0.0;
  const float* xr = x + (size_t)b * DMODEL;
#pragma unroll
  for (int i = 0; i < 4; ++i) {
    float4 xv = *(const float4*)(xr + i * 256 + lane * 4);
#pragma unroll
    for (int e = 0; e < NEXP; ++e) {
      float4 wv = *(const float4*)(gw + e * DMODEL + i * 256 + lane * 4);
      acc[e] += (double)xv.x * wv.x + (double)xv.y * wv.y +
                (double)xv.z * wv.z + (double)xv.w * wv.w;
    }
  }
#pragma unroll
  for (int e = 0; e < NEXP; ++e) {
    double v = acc[e];
    for (int o = 1; o < 64; o <<= 1) v += __shfl_xor(v, o, 64);
    acc[e] = v + (double)gb[e];
  }
  if (lane == 0) {
    int i0 = 0;
    double v0 = acc[0];
#pragma unroll
    for (int e = 1; e < NEXP; ++e)
      if (acc[e] > v0) { v0 = acc[e]; i0 = e; }
    int i1 = -1;
    double v1 = -1e300;
#pragma unroll
    for (int e = 0; e < NEXP; ++e)
      if (e != i0 && acc[e] > v1) { v1 = acc[e]; i1 = e; }
    double t = exp(v1 - v0);
    float s0 = (float)(1.0 / (1.0 + t));
    float s1 = (float)(t / (1.0 + t));
    idx2[b * 2] = i0;
    idx2[b * 2 + 1] = i1;
    sc2[b * 2] = s0;
    sc2[b * 2 + 1] = s1;
  }
}

// ---- route: single block; histogram + stable counting sort + BOTH tile maps ----
__global__ __launch_bounds__(256) void route_kernel(
    const int* __restrict__ idx2, const float* __restrict__ sc2,
    int* __restrict__ tile_map, int* __restrict__ ntiles,
    int* __restrict__ tm256, int* __restrict__ nt256,
    int* __restrict__ pos_of, int* __restrict__ row_of,
    float* __restrict__ s_of) {
  __shared__ int lc[NEXP][257];
  __shared__ int offs[NEXP + 1];
  const int tid = threadIdx.x;
  const int base = tid * 16;
#pragma unroll
  for (int e = 0; e < NEXP; ++e) lc[e][tid + 1] = 0;
  if (tid < NEXP) lc[tid][0] = 0;
  __syncthreads();
  int loc[16];
#pragma unroll
  for (int j = 0; j < 16; ++j) {
    int e = idx2[base + j];
    loc[j] = e;
    atomicAdd(&lc[e][tid + 1], 1);
  }
  __syncthreads();
  if (tid < NEXP) {
    int s = 0;
    for (int i = 1; i <= 256; ++i) {
      s += lc[tid][i];
      lc[tid][i] = s;
    }
  }
  __syncthreads();
  if (tid == 0) {
    offs[0] = 0;
    for (int e = 0; e < NEXP; ++e) offs[e + 1] = offs[e] + lc[e][256];
    int tt = 0, t2 = 0;
    for (int e = 0; e < NEXP; ++e) {
      int cnt = lc[e][256];
      int bse = offs[e];
      for (int t = 0; t * BM < cnt; ++t) {
        tile_map[tt * 4 + 0] = e;
        tile_map[tt * 4 + 1] = bse + t * BM;
        tile_map[tt * 4 + 2] = (cnt - t * BM) < BM ? (cnt - t * BM) : BM;
        tile_map[tt * 4 + 3] = 0;
        ++tt;
      }
      for (int t = 0; t * 256 < cnt; ++t) {
        tm256[t2 * 4 + 0] = e;
        tm256[t2 * 4 + 1] = bse + t * 256;
        tm256[t2 * 4 + 2] = (cnt - t * 256) < 256 ? (cnt - t * 256) : 256;
        tm256[t2 * 4 + 3] = 0;
        ++t2;
      }
    }
    *ntiles = tt;
    *nt256 = t2;
  }
  __syncthreads();
#pragma unroll
  for (int e = 0; e < NEXP; ++e) lc[e][tid] += offs[e];
  __syncthreads();
#pragma unroll
  for (int j = 0; j < 16; ++j) {
    int e = loc[j];
    int p = lc[e][tid];
    lc[e][tid] = p + 1;
    int t = base + j;
    pos_of[t] = p;
    row_of[p] = t >> 1;
    s_of[p] = sc2[t];
  }
}

// ---------------- gather: permuted bf16 activations ----------------
__global__ __launch_bounds__(256) void gather_kernel(
    const float* __restrict__ x, const int* __restrict__ row_of,
    unsigned short* __restrict__ Xp) {
  int r = blockIdx.x;
  int tok = row_of[r];
  int c = threadIdx.x * 4;
  float4 v = *(const float4*)(x + (size_t)tok * DMODEL + c);
  ushort4 o = make_ushort4(f2b(v.x), f2b(v.y), f2b(v.z), f2b(v.w));
  *(ushort4*)(Xp + (size_t)r * DMODEL + c) = o;
}

// ---- transpose+convert: W[e][k][n] f32 -> Wt[e][n][k] bf16 (u32 k-pair pack) ----
__global__ __launch_bounds__(256) void convT_kernel(
    const float* __restrict__ W, unsigned short* __restrict__ Wt, int Kd, int Nd,
    int tilesN, int cpx) {
  __shared__ unsigned L[64 * 33];
  int bidx = (blockIdx.x & 7) * cpx + (blockIdx.x >> 3);
  int nt = bidx % tilesN;
  int r2 = bidx / tilesN;
  int tilesK = Kd >> 6;
  int kt = r2 % tilesK;
  int e = r2 / tilesK;
  int tid = threadIdx.x;

  const float* src = W + (long)e * Kd * Nd + (long)(kt * 64) * Nd + nt * 64;
  int kp = tid >> 3;
  int nb = tid & 7;
  const float* r0 = src + (long)(2 * kp) * Nd + nb * 8;
  const float* r1 = r0 + Nd;
  float4 va0 = *(const float4*)r0;
  float4 va1 = *(const float4*)(r0 + 4);
  float4 vb0 = *(const float4*)r1;
  float4 vb1 = *(const float4*)(r1 + 4);
  const float* a = (const float*)&va0;
  const float* bq = (const float*)&vb0;
#pragma unroll
  for (int j = 0; j < 4; ++j) {
    unsigned p = (unsigned)f2b(a[j]) | ((unsigned)f2b(bq[j]) << 16);
    L[(nb * 8 + j) * 33 + kp] = p;
  }
  const float* a2 = (const float*)&va1;
  const float* b2 = (const float*)&vb1;
#pragma unroll
  for (int j = 0; j < 4; ++j) {
    unsigned p = (unsigned)f2b(a2[j]) | ((unsigned)f2b(b2[j]) << 16);
    L[(nb * 8 + 4 + j) * 33 + kp] = p;
  }
  __syncthreads();
  int n = tid >> 2;
  int part = tid & 3;
  unsigned q[8];
#pragma unroll
  for (int j = 0; j < 8; ++j) q[j] = L[n * 33 + part * 8 + j];
  unsigned* dst = (unsigned*)(Wt + (long)e * Nd * Kd + (long)(nt * 64 + n) * Kd +
                              kt * 64) +
                  part * 8;
  *(uint4*)dst = make_uint4(q[0], q[1], q[2], q[3]);
  *(uint4*)(dst + 4) = make_uint4(q[4], q[5], q[6], q[7]);
}

// ------- G1: 256x128 tile, 512 threads (8 waves 4Mx2N), single-buffer -------
__global__ __launch_bounds__(512) void gemm1_wide(
    const unsigned short* __restrict__ A, int lda,
    const unsigned short* __restrict__ Bt, long strideB,
    const float* __restrict__ bias, unsigned short* __restrict__ Cout, int ldc,
    const int* __restrict__ tm256, const int* __restrict__ nt256, int N,
    int K) {
  const int nb = N / 128;
  const int tile = blockIdx.x / nb;
  if (tile >= *nt256) return;
  const int ct = blockIdx.x % nb;
  const int e = tm256[tile * 4 + 0];
  const int row0 = tm256[tile * 4 + 1];
  const int rows = tm256[tile * 4 + 2];
  const int n0 = ct * 128;
  const unsigned short* B_e = Bt + (long)e * strideB + (long)n0 * K;

  __shared__ __align__(16) unsigned short Asm[256 * BK];
  __shared__ __align__(16) unsigned short Bsm[128 * BK];

  const int tid = threadIdx.x;
  const int lane = tid & 63;
  const int w = tid >> 6;
  const int wr = (w >> 1) * 64;
  const int wc = (w & 1) * 64;
  const int l15 = lane & 15;
  const int l4 = lane >> 4;

  f32x4 acc[4][4] = {};

  for (int k0 = 0; k0 < K; k0 += BK) {
#pragma unroll
    for (int it = 0; it < 4; ++it) {
      int c = it * 512 + tid;
      int r = c >> 3, kc = c & 7;
      int kcs = kc ^ (r & 7);
      load_lds16(A + (size_t)(row0 + r) * lda + k0 + kcs * 8,
                 ((char*)Asm) + (size_t)(it * 512 + w * 64) * 16);
    }
#pragma unroll
    for (int it = 0; it < 2; ++it) {
      int c = it * 512 + tid;
      int r = c >> 3, kc = c & 7;
      int kcs = kc ^ (r & 7);
      load_lds16(B_e + (size_t)r * K + k0 + kcs * 8,
                 ((char*)Bsm) + (size_t)(it * 512 + w * 64) * 16);
    }
    __syncthreads();
#pragma unroll
    for (int kk = 0; kk < 2; ++kk) {
      bf16x8 a[4], b[4];
#pragma unroll
      for (int m = 0; m < 4; ++m) {
        int row = wr + m * 16 + l15;
        int ch = (kk * 4 + l4) ^ (l15 & 7);
        a[m] = *(const bf16x8*)&Asm[row * BK + ch * 8];
      }
#pragma unroll
      for (int n = 0; n < 4; ++n) {
        int row = wc + n * 16 + l15;
        int ch = (kk * 4 + l4) ^ (l15 & 7);
        b[n] = *(const bf16x8*)&Bsm[row * BK + ch * 8];
      }
#pragma unroll
      for (int m = 0; m < 4; ++m)
#pragma unroll
        for (int n = 0; n < 4; ++n)
          acc[m][n] =
              __builtin_amdgcn_mfma_f32_16x16x32_bf16(a[m], b[n], acc[m][n], 0, 0, 0);
    }
    __syncthreads();
  }

  const float* bias_e = bias + (long)e * HDIM;
#pragma unroll
  for (int m = 0; m < 4; ++m) {
#pragma unroll
    for (int i = 0; i < 4; ++i) {
      int r = wr + m * 16 + l4 * 4 + i;
      if (r < rows) {
        size_t grow = (size_t)(row0 + r) * ldc;
#pragma unroll
        for (int n = 0; n < 4; ++n) {
          int cg = n0 + wc + n * 16 + l15;
          float v = acc[m][n][i] + bias_e[cg];
          v = gelu_fast(v);
          Cout[grow + cg] = f2b(v);
        }
      }
    }
  }
}

// ------- G2: 128x64, double-buffered + COUNTED vmcnt (T3/T4 mechanism) -------
// Per thread per stage: 4 A-loads + 2 B-loads = 6 global_load_lds.
// Loop waits vmcnt(6): tile-t loads landed, tile-(t+1) loads stay in flight.
// Raw s_barrier (no drain). Buffer reuse protected by post-compute barrier.
__global__ __launch_bounds__(256) void gemm2_db(
    const unsigned short* __restrict__ A,   // H1 [rows][4096]
    const unsigned short* __restrict__ Bt,  // Wt2 [E][1024][4096]
    const float* __restrict__ bias, float* __restrict__ out,
    const int* __restrict__ row_of, const float* __restrict__ s_of,
    const int* __restrict__ tile_map, const int* __restrict__ ntiles) {
  const int K = HDIM, N = DMODEL;
  const int nb = N / 64;
  const int tile = blockIdx.x / nb;
  if (tile >= *ntiles) return;
  const int ct = blockIdx.x % nb;
  const int e = tile_map[tile * 4 + 0];
  const int row0 = tile_map[tile * 4 + 1];
  const int rows = tile_map[tile * 4 + 2];
  const int n0 = ct * 64;
  const unsigned short* B_e = Bt + (long)e * N * K + (long)n0 * K;

  __shared__ __align__(16) unsigned short Asm[2][BM * BK];
  __shared__ __align__(16) unsigned short Bsm[2][64 * BK];

  const int tid = threadIdx.x;
  const int lane = tid & 63;
  const int w = tid >> 6;
  const int wr = w * 32;  // 4 waves x 32 rows, full 64-col width
  const int l15 = lane & 15;
  const int l4 = lane >> 4;
  const int rA = tid >> 3, kcA = tid & 7;

  f32x4 acc[2][4] = {};

#define STAGE2D(buf, k0)                                                      \
  {                                                                           \
    _Pragma("unroll") for (int it = 0; it < 4; ++it) {                        \
      int r = it * 32 + rA;                                                   \
      int kcs = kcA ^ (r & 7);                                                \
      load_lds16(A + (size_t)(row0 + r) * K + (k0) + kcs * 8,                 \
                 ((char*)Asm[buf]) + (size_t)(it * 256 + w * 64) * 16);       \
    }                                                                         \
    _Pragma("unroll") for (int it = 0; it < 2; ++it) {                        \
      int r = it * 32 + rA;                                                   \
      int kcs = kcA ^ (r & 7);                                                \
      load_lds16(B_e + (size_t)r * K + (k0) + kcs * 8,                        \
                 ((char*)Bsm[buf]) + (size_t)(it * 256 + w * 64) * 16);       \
    }                                                                         \
  }

#define COMPUTE2D(buf)                                                        \
  {                                                                           \
    _Pragma("unroll") for (int kk = 0; kk < 2; ++kk) {                        \
      bf16x8 a[2], b[4];                                                      \
      _Pragma("unroll") for (int m = 0; m < 2; ++m) {                         \
        int row = wr + m * 16 + l15;                                          \
        int ch = (kk * 4 + l4) ^ (l15 & 7);                                   \
        a[m] = *(const bf16x8*)&Asm[buf][row * BK + ch * 8];                  \
      }                                                                       \
      _Pragma("unroll") for (int n = 0; n < 4; ++n) {                         \
        int row = n * 16 + l15;                                               \
        int ch = (kk * 4 + l4) ^ (l15 & 7);                                   \
        b[n] = *(const bf16x8*)&Bsm[buf][row * BK + ch * 8];                  \
      }                                                                       \
      _Pragma("unroll") for (int m = 0; m < 2; ++m)                           \
          _Pragma("unroll") for (int n = 0; n < 4; ++n) acc[m][n] =           \
              __builtin_amdgcn_mfma_f32_16x16x32_bf16(a[m], b[n], acc[m][n],  \
                                                      0, 0, 0);               \
    }                                                                         \
  }

  const int nsteps = K / BK;  // 64
  STAGE2D(0, 0);
  STAGE2D(1, BK);
#pragma unroll 1
  for (int t = 0; t < nsteps - 1; ++t) {
    asm volatile("s_waitcnt vmcnt(6)" ::: "memory");
    __builtin_amdgcn_s_barrier();
    COMPUTE2D(t & 1);
    __builtin_amdgcn_s_barrier();
    if (t + 2 < nsteps) STAGE2D(t & 1, (t + 2) * BK);
  }
  asm volatile("s_waitcnt vmcnt(0)" ::: "memory");
  __builtin_amdgcn_s_barrier();
  COMPUTE2D((nsteps - 1) & 1);
#undef STAGE2D
#undef COMPUTE2D

  const float* bias_e = bias + (long)e * DMODEL;
#pragma unroll
  for (int m = 0; m < 2; ++m) {
#pragma unroll
    for (int i = 0; i < 4; ++i) {
      int r = wr + m * 16 + l4 * 4 + i;
      if (r < rows) {
        int tok = row_of[row0 + r];
        float s = s_of[row0 + r];
        float* op = out + (size_t)tok * DMODEL;
#pragma unroll
        for (int n = 0; n < 4; ++n) {
          int cg = n0 + n * 16 + l15;
          float v = acc[m][n][i] + bias_e[cg];
          atomicAdd(&op[cg], s * v);
        }
      }
    }
  }
}

extern "C" void kernel_launch(void* const* d_in, const int* in_sizes, int n_in,
                              void* d_out, int out_size, void* d_ws, size_t ws_size,
                              hipStream_t stream) {
  const float* x = (const float*)d_in[0];
  const float* gw = (const float*)d_in[1];
  const float* gb = (const float*)d_in[2];
  const float* w1 = (const float*)d_in[3];
  const float* b1 = (const float*)d_in[4];
  const float* w2 = (const float*)d_in[5];
  const float* b2 = (const float*)d_in[6];
  float* out = (float*)d_out;
  char* ws = (char*)d_ws;

  int* ntiles = (int*)(ws + 128);
  int* nt256 = (int*)(ws + 132);
  int* tile_map = (int*)(ws + 256);
  int* tm256 = (int*)(ws + 2048);
  int* idx2 = (int*)(ws + 4096);
  float* sc2 = (float*)(ws + 20480);
  int* pos_of = (int*)(ws + 36864);
  int* row_of = (int*)(ws + 53248);
  float* s_of = (float*)(ws + 73728);
  unsigned short* Xp = (unsigned short*)(ws + 131072);    // 4224x1024 bf16
  unsigned short* H1 = (unsigned short*)(ws + 8781824);   // 4224x4096 bf16
  unsigned short* Wt = (unsigned short*)(ws + 43384832);  // 8x4096x1024 bf16
  if (ws_size < 110493696ULL) return;

  gate_kernel<<<B_TOK / 4, 256, 0, stream>>>(x, gw, gb, idx2, sc2, out);
  route_kernel<<<1, 256, 0, stream>>>(idx2, sc2, tile_map, ntiles, tm256, nt256,
                                      pos_of, row_of, s_of);
  gather_kernel<<<B_TOK * TOPK, 256, 0, stream>>>(x, row_of, Xp);

  // w1 [E][D][H] f32 -> Wt [E][H][D] bf16  (grid 8192, cpx=1024)
  convT_kernel<<<NEXP * (DMODEL / 64) * (HDIM / 64), 256, 0, stream>>>(
      w1, Wt, DMODEL, HDIM, HDIM / 64, NEXP * (DMODEL / 64) * (HDIM / 64) / 8);
  // G1: 256x128 wide tile
  gemm1_wide<<<MAX_T256 * (HDIM / 128), 512, 0, stream>>>(
      Xp, DMODEL, Wt, (long)HDIM * DMODEL, b1, H1, HDIM, tm256, nt256, HDIM,
      DMODEL);
  // w2 [E][H][D] f32 -> Wt [E][D][H] bf16 (reuse buffer; grid 8192, cpx=1024)
  convT_kernel<<<NEXP * (HDIM / 64) * (DMODEL / 64), 256, 0, stream>>>(
      w2, Wt, HDIM, DMODEL, DMODEL / 64, NEXP * (HDIM / 64) * (DMODEL / 64) / 8);
  // G2: double-buffered + counted vmcnt (T4), fused atomic combine
  gemm2_db<<<MAX_TILES * (DMODEL / 64), 256, 0, stream>>>(
      H1, Wt, b2, out, row_of, s_of, tile_map, ntiles);
}